// Round 1
// baseline (901.321 us; speedup 1.0000x reference)
//
#include <hip/hip_runtime.h>

// AttractorNetwork LIF simulation, one workgroup per batch row.
// noise layout: [STEPS, BATCH, N]; cue [BATCH, N]; W [N, N]; out [BATCH, N].
//
// Per step: rec = last_spk @ ((W - inh/N) * (1-eye))
//   computed as gather-sum over the spiking-index list (spikes are binary),
//   with corrections: subtract k*c (inhibition term per spike) and, if this
//   neuron itself spiked last step, subtract (W[n][n] - c) (self-mask).

constexpr int N   = 2048;   // neurons
constexpr int PT  = 8;      // neurons per thread
constexpr int BLK = N / PT; // 256 threads

__global__ __launch_bounds__(BLK)
void attractor_sim(const float* __restrict__ cue,
                   const float* __restrict__ W,
                   const float* __restrict__ noise,
                   const int*   __restrict__ steps_p,
                   const int*   __restrict__ cuedur_p,
                   float*       __restrict__ out,
                   int batch)
{
    const int b    = blockIdx.x;
    const int tid  = threadIdx.x;
    const int base = tid * PT;

    __shared__ unsigned short lst[2][N];
    __shared__ int cnt[2];
    if (tid == 0) { cnt[0] = 0; cnt[1] = 0; }

    const int   steps  = *steps_p;      // 200
    const int   cuedur = *cuedur_p;     // 10
    const int   half   = steps / 2;
    const float decay  = (float)0.95122942450071400910; // exp(-DT/TAU_MEM) as f32
    const float C_INH  = 0.1f / 2048.0f;                // INHIBITION / N (exact pow2 scale)

    // cue row (CUE_STRENGTH = 1.0)
    const float4 cA = *(const float4*)(cue + (size_t)b * N + base);
    const float4 cB = *(const float4*)(cue + (size_t)b * N + base + 4);
    const float  ce[PT] = {cA.x, cA.y, cA.z, cA.w, cB.x, cB.y, cB.z, cB.w};

    // diagonal weights (for self-mask correction), loaded once
    float wdiag[PT];
    #pragma unroll
    for (int u = 0; u < PT; ++u)
        wdiag[u] = W[(size_t)(base + u) * N + (base + u)];

    float mem[PT] = {0,0,0,0,0,0,0,0};
    float acc[PT] = {0,0,0,0,0,0,0,0};
    unsigned lastspk = 0;  // bitmask over my PT neurons

    const size_t stepstride = (size_t)batch * N;
    const float* nzp = noise + (size_t)b * N + base;

    // noise for step 0 (prefetched)
    float4 n0 = *(const float4*)(nzp);
    float4 n1 = *(const float4*)(nzp + 4);

    __syncthreads();

    int p = 0;
    for (int t = 0; t < steps; ++t) {
        // ---- prefetch next step's noise (independent of this step's work) ----
        float4 m0 = n0, m1 = n1;
        if (t + 1 < steps) {
            const float* q4 = nzp + (size_t)(t + 1) * stepstride;
            m0 = *(const float4*)(q4);
            m1 = *(const float4*)(q4 + 4);
        }

        // ---- recurrent input: gather-sum over spiking list of step t-1 ----
        const int k = cnt[p];
        const unsigned short* lp = lst[p];
        float r[PT] = {0,0,0,0,0,0,0,0};
        for (int i = 0; i < k; ++i) {
            const int j = lp[i];
            const float4* wr = (const float4*)(W + (size_t)j * N + base);
            const float4 a  = wr[0];
            const float4 c2 = wr[1];
            r[0] += a.x;  r[1] += a.y;  r[2] += a.z;  r[3] += a.w;
            r[4] += c2.x; r[5] += c2.y; r[6] += c2.z; r[7] += c2.w;
        }

        const float corr   = (float)k * C_INH;
        const bool  in_cue = (t < cuedur);
        const float nz[PT] = {n0.x, n0.y, n0.z, n0.w, n1.x, n1.y, n1.z, n1.w};

        unsigned newspk = 0;
        const int q = p ^ 1;
        #pragma unroll
        for (int u = 0; u < PT; ++u) {
            float rec = r[u] - corr;
            if (lastspk & (1u << u)) rec -= (wdiag[u] - C_INH);
            const float ext = in_cue ? ce[u] : 0.0f;
            const float m   = mem[u] * decay + (rec + ext) + nz[u];
            if (m >= 1.0f) {                       // spike: hard reset
                mem[u] = 0.0f;
                newspk |= (1u << u);
                const int pos = atomicAdd(&cnt[q], 1);
                lst[q][pos] = (unsigned short)(base + u);
                if (t >= half) acc[u] += 1.0f;
            } else {
                mem[u] = m;
            }
        }
        lastspk = newspk;

        __syncthreads();             // appends to buf q done; reads of buf p done
        if (tid == 0) cnt[p] = 0;    // recycle p as next step's write buffer
        __syncthreads();             // reset visible before next step's appends
        p = q;
        n0 = m0; n1 = m1;
    }

    // ---- epilogue: mean activity over second half ----
    const float h = (float)half;
    float4 o0, o1;
    o0.x = acc[0] / h; o0.y = acc[1] / h; o0.z = acc[2] / h; o0.w = acc[3] / h;
    o1.x = acc[4] / h; o1.y = acc[5] / h; o1.z = acc[6] / h; o1.w = acc[7] / h;
    float* op = out + (size_t)b * N + base;
    *(float4*)(op)     = o0;
    *(float4*)(op + 4) = o1;
}

extern "C" void kernel_launch(void* const* d_in, const int* in_sizes, int n_in,
                              void* d_out, int out_size, void* d_ws, size_t ws_size,
                              hipStream_t stream) {
    const float* cue    = (const float*)d_in[0];
    const float* W      = (const float*)d_in[1];
    const float* noise  = (const float*)d_in[2];
    const int*   steps  = (const int*)d_in[3];
    const int*   cuedur = (const int*)d_in[4];
    float*       out    = (float*)d_out;

    const int batch = in_sizes[0] / N;   // 128
    attractor_sim<<<batch, BLK, 0, stream>>>(cue, W, noise, steps, cuedur, out, batch);
}

// Round 2
// 524.187 us; speedup vs baseline: 1.7195x; 1.7195x over previous
//
#include <hip/hip_runtime.h>

// AttractorNetwork LIF simulation, one workgroup per batch row.
// noise layout: [STEPS, BATCH, N]; cue [BATCH, N]; W [N, N]; out [BATCH, N].
//
// rec = last_spk @ ((W - inh/N) * (1-eye)) computed as a gather-sum over the
// spike index list (spikes are binary):
//   rec[n] = sum_{j in S} W[j][n] - k*c  - (self ? (W[n][n]-c) : 0),  c = inh/N
//
// Latency-optimized: 8-wide unrolled gather (8 independent W-row loads in
// flight), 512 threads (8 waves) per block, non-temporal noise stream (keeps
// W resident in L3), depth-2 noise prefetch via static 3-register rotation,
// single barrier per step via 3-buffer spike-list rotation.

typedef float        f32x4 __attribute__((ext_vector_type(4)));
typedef unsigned int u32x4 __attribute__((ext_vector_type(4)));

constexpr int N   = 2048;   // neurons
constexpr int PT  = 4;      // neurons per thread
constexpr int BLK = N / PT; // 512 threads = 8 waves

__device__ __forceinline__ f32x4 ntload4(const float* p) {
    return __builtin_nontemporal_load(reinterpret_cast<const f32x4*>(p));
}

__global__ __launch_bounds__(BLK)
void attractor_sim(const float* __restrict__ cue,
                   const float* __restrict__ W,
                   const float* __restrict__ noise,
                   const int*   __restrict__ steps_p,
                   const int*   __restrict__ cuedur_p,
                   float*       __restrict__ out,
                   int batch)
{
    const int b    = blockIdx.x;
    const int tid  = threadIdx.x;
    const int base = tid * PT;

    __shared__ __align__(16) unsigned short lst[3][N];
    __shared__ int cnt[3];
    if (tid < 3) cnt[tid] = 0;

    const int   steps  = *steps_p;      // 200
    const int   cuedur = *cuedur_p;     // 10
    const int   half   = steps / 2;
    const float decay  = 0.95122942450071400910f; // exp(-DT/TAU_MEM) as f32
    const float C_INH  = 0.1f / 2048.0f;          // INHIBITION / N

    // cue row (CUE_STRENGTH = 1.0)
    const f32x4 ce = *reinterpret_cast<const f32x4*>(cue + (size_t)b * N + base);

    // diagonal weights for the self-mask correction
    float wdiag[PT];
    #pragma unroll
    for (int u = 0; u < PT; ++u)
        wdiag[u] = W[(size_t)(base + u) * N + (base + u)];

    f32x4 mem = {0.f, 0.f, 0.f, 0.f};
    f32x4 acc = {0.f, 0.f, 0.f, 0.f};
    unsigned lastspk = 0;

    const size_t stepstride = (size_t)batch * N;
    const float* nzp = noise + (size_t)b * N + base;

    // noise pipeline registers: n0 holds t, n1 holds t+1 (depth-2 prefetch)
    f32x4 n0 = ntload4(nzp);
    f32x4 n1 = ntload4(nzp + (size_t)(steps > 1 ? 1 : 0) * stepstride);
    f32x4 n2;

    __syncthreads();

    // one simulation step; nUse = noise(t), nFill receives noise(t+2)
    auto body = [&](int t, f32x4& nUse, f32x4& nFill, int ra, int wb, int rc) {
        // prefetch noise two steps ahead (clamped; surplus values unused)
        const int tpre = (t + 2 < steps) ? (t + 2) : (steps - 1);
        nFill = ntload4(nzp + (size_t)tpre * stepstride);

        const int k = cnt[ra];
        if (tid == 0) cnt[rc] = 0;   // rc is idle this step; visible after barrier
        const unsigned short* lp = lst[ra];

        // gather-sum over spiking rows, 8 rows in flight
        f32x4 r = {0.f, 0.f, 0.f, 0.f};
        int i = 0;
        for (; i + 8 <= k; i += 8) {
            const u32x4 iv = *reinterpret_cast<const u32x4*>(lp + i);
            const int j0 = (int)(iv[0] & 0xffffu), j1 = (int)(iv[0] >> 16);
            const int j2 = (int)(iv[1] & 0xffffu), j3 = (int)(iv[1] >> 16);
            const int j4 = (int)(iv[2] & 0xffffu), j5 = (int)(iv[2] >> 16);
            const int j6 = (int)(iv[3] & 0xffffu), j7 = (int)(iv[3] >> 16);
            const f32x4 w0 = *reinterpret_cast<const f32x4*>(W + j0 * N + base);
            const f32x4 w1 = *reinterpret_cast<const f32x4*>(W + j1 * N + base);
            const f32x4 w2 = *reinterpret_cast<const f32x4*>(W + j2 * N + base);
            const f32x4 w3 = *reinterpret_cast<const f32x4*>(W + j3 * N + base);
            const f32x4 w4 = *reinterpret_cast<const f32x4*>(W + j4 * N + base);
            const f32x4 w5 = *reinterpret_cast<const f32x4*>(W + j5 * N + base);
            const f32x4 w6 = *reinterpret_cast<const f32x4*>(W + j6 * N + base);
            const f32x4 w7 = *reinterpret_cast<const f32x4*>(W + j7 * N + base);
            // list-order accumulation (numerics identical to round-1 kernel)
            r += w0; r += w1; r += w2; r += w3;
            r += w4; r += w5; r += w6; r += w7;
        }
        for (; i < k; ++i) {
            const int j = lp[i];
            r += *reinterpret_cast<const f32x4*>(W + j * N + base);
        }

        const float corr   = (float)k * C_INH;
        const bool  in_cue = (t < cuedur);

        unsigned newspk = 0;
        #pragma unroll
        for (int u = 0; u < PT; ++u) {
            float rec = r[u] - corr;
            if (lastspk & (1u << u)) rec -= (wdiag[u] - C_INH);
            const float ext = in_cue ? ce[u] : 0.0f;
            const float m   = mem[u] * decay + (rec + ext) + nUse[u];
            if (m >= 1.0f) {                     // spike: hard reset
                mem[u] = 0.0f;
                newspk |= (1u << u);
                const int pos = atomicAdd(&cnt[wb], 1);
                lst[wb][pos] = (unsigned short)(base + u);
                if (t >= half) acc[u] += 1.0f;
            } else {
                mem[u] = m;
            }
        }
        lastspk = newspk;

        __syncthreads();   // appends to wb done; reads of ra done; reset of rc visible
    };

    int t = 0;
    for (; t + 3 <= steps; t += 3) {
        body(t,     n0, n2, 0, 1, 2);
        body(t + 1, n1, n0, 1, 2, 0);
        body(t + 2, n2, n1, 2, 0, 1);
    }
    for (; t < steps; ++t) {
        switch (t % 3) {
            case 0: body(t, n0, n2, 0, 1, 2); break;
            case 1: body(t, n1, n0, 1, 2, 0); break;
            default: body(t, n2, n1, 2, 0, 1); break;
        }
    }

    // epilogue: mean activity over second half
    const float h = (float)half;
    f32x4 o;
    o[0] = acc[0] / h; o[1] = acc[1] / h; o[2] = acc[2] / h; o[3] = acc[3] / h;
    float* op = out + (size_t)b * N + base;
    __builtin_nontemporal_store(o, reinterpret_cast<f32x4*>(op));
}

extern "C" void kernel_launch(void* const* d_in, const int* in_sizes, int n_in,
                              void* d_out, int out_size, void* d_ws, size_t ws_size,
                              hipStream_t stream) {
    const float* cue    = (const float*)d_in[0];
    const float* W      = (const float*)d_in[1];
    const float* noise  = (const float*)d_in[2];
    const int*   steps  = (const int*)d_in[3];
    const int*   cuedur = (const int*)d_in[4];
    float*       out    = (float*)d_out;

    const int batch = in_sizes[0] / N;   // 128
    attractor_sim<<<batch, BLK, 0, stream>>>(cue, W, noise, steps, cuedur, out, batch);
}

// Round 3
// 497.655 us; speedup vs baseline: 1.8111x; 1.0533x over previous
//
#include <hip/hip_runtime.h>

// AttractorNetwork LIF, one workgroup per batch row.
// rec = last_spk @ ((W - inh/N)*(1-eye)) as a gather-sum over spike indices:
//   rec[n] = sum_{j in S} W[j][n] - k*c - (self ? (W[n][n]-c) : 0), c = inh/N
// W pre-converted to bf16 in d_ws (halves gather volume; subcritical dynamics
// are robust to 5e-4 perturbation, and the quiet-phase k=0 path is exact).
// 8-wide MLP gather, depth-4 noise prefetch, ballot spike compaction,
// 3-buffer spike list (1 barrier/step).

typedef float          f32x4 __attribute__((ext_vector_type(4)));
typedef unsigned int   u32x4 __attribute__((ext_vector_type(4)));
typedef unsigned int   u32x2 __attribute__((ext_vector_type(2)));
typedef unsigned short u16x8 __attribute__((ext_vector_type(8)));

constexpr int N   = 2048;   // neurons
constexpr int PT  = 4;      // neurons per thread
constexpr int BLK = N / PT; // 512 threads = 8 waves

__device__ __forceinline__ f32x4 ntload4(const float* p) {
    return __builtin_nontemporal_load(reinterpret_cast<const f32x4*>(p));
}
__device__ __forceinline__ float bf2f(unsigned b) {
    return __builtin_bit_cast(float, b << 16);
}
__device__ __forceinline__ void addrow_bf(f32x4& r, u32x2 v) {
    r[0] += __builtin_bit_cast(float, v[0] << 16);
    r[1] += __builtin_bit_cast(float, v[0] & 0xffff0000u);
    r[2] += __builtin_bit_cast(float, v[1] << 16);
    r[3] += __builtin_bit_cast(float, v[1] & 0xffff0000u);
}

// ---- W f32 -> bf16 (RNE) pre-pass: 2048 blocks x 256 thr x 8 elems ----
__global__ __launch_bounds__(256)
void conv_bf16(const float* __restrict__ W, unsigned short* __restrict__ Wb) {
    const size_t i = ((size_t)blockIdx.x * 256 + threadIdx.x) * 8;
    const f32x4 a = *reinterpret_cast<const f32x4*>(W + i);
    const f32x4 b = *reinterpret_cast<const f32x4*>(W + i + 4);
    u16x8 o;
    #pragma unroll
    for (int u = 0; u < 4; ++u) {
        const unsigned x = __builtin_bit_cast(unsigned, a[u]);
        o[u] = (unsigned short)((x + 0x7fffu + ((x >> 16) & 1u)) >> 16);
    }
    #pragma unroll
    for (int u = 0; u < 4; ++u) {
        const unsigned x = __builtin_bit_cast(unsigned, b[u]);
        o[4 + u] = (unsigned short)((x + 0x7fffu + ((x >> 16) & 1u)) >> 16);
    }
    *reinterpret_cast<u16x8*>(Wb + i) = o;
}

// WM=1: bf16 gather from Wb; WM=0: f32 gather from W (ws fallback)
template <int WM>
__global__ __launch_bounds__(BLK)
void attractor_sim(const float* __restrict__ cue,
                   const float* __restrict__ W,
                   const unsigned short* __restrict__ Wb,
                   const float* __restrict__ noise,
                   const int*   __restrict__ steps_p,
                   const int*   __restrict__ cuedur_p,
                   float*       __restrict__ out,
                   int batch)
{
    const int b    = blockIdx.x;
    const int tid  = threadIdx.x;
    const int base = tid * PT;
    const int lane = tid & 63;

    __shared__ __align__(16) unsigned short lst[3][N];
    __shared__ int cnt[3];
    if (tid < 3) cnt[tid] = 0;

    const int   steps  = *steps_p;      // 200
    const int   cuedur = *cuedur_p;     // 10
    const int   half   = steps / 2;
    const float decay  = 0.95122942450071400910f; // exp(-DT/TAU_MEM) as f32
    const float C_INH  = 0.1f / 2048.0f;

    const f32x4 ce = *reinterpret_cast<const f32x4*>(cue + (size_t)b * N + base);

    // diagonal (self-mask correction) — from the SAME array the gather reads,
    // so the self contribution cancels exactly.
    float wdiag[PT];
    #pragma unroll
    for (int u = 0; u < PT; ++u) {
        const size_t d = (size_t)(base + u) * N + (base + u);
        wdiag[u] = (WM == 1) ? bf2f((unsigned)Wb[d]) : W[d];
    }

    f32x4 mem = {0.f, 0.f, 0.f, 0.f};
    f32x4 acc = {0.f, 0.f, 0.f, 0.f};
    unsigned lastspk = 0;

    const size_t ss  = (size_t)batch * N;
    const float* nzp = noise + (size_t)b * N + base;

    // depth-4 noise pipeline
    f32x4 n0 = ntload4(nzp + (size_t)((0 < steps) ? 0 : steps - 1) * ss);
    f32x4 n1 = ntload4(nzp + (size_t)((1 < steps) ? 1 : steps - 1) * ss);
    f32x4 n2 = ntload4(nzp + (size_t)((2 < steps) ? 2 : steps - 1) * ss);
    f32x4 n3 = ntload4(nzp + (size_t)((3 < steps) ? 3 : steps - 1) * ss);

    int ra = 0, wb = 1, rc = 2;   // read / write / idle spike-list buffers

    __syncthreads();

    auto body = [&](int t, f32x4& nReg) {
        const f32x4 cur = nReg;
        const int tp = (t + 4 < steps) ? (t + 4) : (steps - 1);
        nReg = ntload4(nzp + (size_t)tp * ss);   // refill 4 steps ahead

        const int k = cnt[ra];
        if (tid == 0) cnt[rc] = 0;               // idle buf; visible after barrier
        const unsigned short* lp = lst[ra];

        f32x4 r = {0.f, 0.f, 0.f, 0.f};
        int i = 0;
        if (WM == 1) {
            for (; i + 8 <= k; i += 8) {
                const u32x4 iv = *reinterpret_cast<const u32x4*>(lp + i);
                const int j0 = (int)(iv[0] & 0xffffu), j1 = (int)(iv[0] >> 16);
                const int j2 = (int)(iv[1] & 0xffffu), j3 = (int)(iv[1] >> 16);
                const int j4 = (int)(iv[2] & 0xffffu), j5 = (int)(iv[2] >> 16);
                const int j6 = (int)(iv[3] & 0xffffu), j7 = (int)(iv[3] >> 16);
                const u32x2 v0 = *reinterpret_cast<const u32x2*>(Wb + (size_t)j0 * N + base);
                const u32x2 v1 = *reinterpret_cast<const u32x2*>(Wb + (size_t)j1 * N + base);
                const u32x2 v2 = *reinterpret_cast<const u32x2*>(Wb + (size_t)j2 * N + base);
                const u32x2 v3 = *reinterpret_cast<const u32x2*>(Wb + (size_t)j3 * N + base);
                const u32x2 v4 = *reinterpret_cast<const u32x2*>(Wb + (size_t)j4 * N + base);
                const u32x2 v5 = *reinterpret_cast<const u32x2*>(Wb + (size_t)j5 * N + base);
                const u32x2 v6 = *reinterpret_cast<const u32x2*>(Wb + (size_t)j6 * N + base);
                const u32x2 v7 = *reinterpret_cast<const u32x2*>(Wb + (size_t)j7 * N + base);
                addrow_bf(r, v0); addrow_bf(r, v1); addrow_bf(r, v2); addrow_bf(r, v3);
                addrow_bf(r, v4); addrow_bf(r, v5); addrow_bf(r, v6); addrow_bf(r, v7);
            }
            for (; i < k; ++i) {
                const u32x2 v = *reinterpret_cast<const u32x2*>(Wb + (size_t)lp[i] * N + base);
                addrow_bf(r, v);
            }
        } else {
            for (; i + 8 <= k; i += 8) {
                const u32x4 iv = *reinterpret_cast<const u32x4*>(lp + i);
                const int j0 = (int)(iv[0] & 0xffffu), j1 = (int)(iv[0] >> 16);
                const int j2 = (int)(iv[1] & 0xffffu), j3 = (int)(iv[1] >> 16);
                const int j4 = (int)(iv[2] & 0xffffu), j5 = (int)(iv[2] >> 16);
                const int j6 = (int)(iv[3] & 0xffffu), j7 = (int)(iv[3] >> 16);
                const f32x4 w0 = *reinterpret_cast<const f32x4*>(W + (size_t)j0 * N + base);
                const f32x4 w1 = *reinterpret_cast<const f32x4*>(W + (size_t)j1 * N + base);
                const f32x4 w2 = *reinterpret_cast<const f32x4*>(W + (size_t)j2 * N + base);
                const f32x4 w3 = *reinterpret_cast<const f32x4*>(W + (size_t)j3 * N + base);
                const f32x4 w4 = *reinterpret_cast<const f32x4*>(W + (size_t)j4 * N + base);
                const f32x4 w5 = *reinterpret_cast<const f32x4*>(W + (size_t)j5 * N + base);
                const f32x4 w6 = *reinterpret_cast<const f32x4*>(W + (size_t)j6 * N + base);
                const f32x4 w7 = *reinterpret_cast<const f32x4*>(W + (size_t)j7 * N + base);
                r += w0; r += w1; r += w2; r += w3;
                r += w4; r += w5; r += w6; r += w7;
            }
            for (; i < k; ++i)
                r += *reinterpret_cast<const f32x4*>(W + (size_t)lp[i] * N + base);
        }

        const float corr   = (float)k * C_INH;
        const bool  in_cue = (t < cuedur);

        unsigned newspk = 0;
        bool sp[PT];
        #pragma unroll
        for (int u = 0; u < PT; ++u) {
            float rec = r[u] - corr;
            if (lastspk & (1u << u)) rec -= (wdiag[u] - C_INH);
            const float ext = in_cue ? ce[u] : 0.0f;
            const float m   = mem[u] * decay + (rec + ext) + cur[u];
            sp[u] = (m >= 1.0f);
            if (sp[u]) {
                mem[u] = 0.0f;
                newspk |= (1u << u);
                if (t >= half) acc[u] += 1.0f;
            } else {
                mem[u] = m;
            }
        }
        lastspk = newspk;

        // per-wave ballot compaction: 1 atomic per wave per sub-neuron slot
        #pragma unroll
        for (int u = 0; u < PT; ++u) {
            const unsigned long long msk = __ballot(sp[u]);
            if (msk) {
                int wpos;
                if (lane == 0) wpos = atomicAdd(&cnt[wb], __popcll(msk));
                wpos = __shfl(wpos, 0);
                if (sp[u]) {
                    const int off = __popcll(msk & ((1ull << lane) - 1ull));
                    lst[wb][wpos + off] = (unsigned short)(base + u);
                }
            }
        }

        __syncthreads();
        const int t0 = ra; ra = wb; wb = rc; rc = t0;
    };

    int t = 0;
    for (; t + 4 <= steps; t += 4) {
        body(t,     n0);
        body(t + 1, n1);
        body(t + 2, n2);
        body(t + 3, n3);
    }
    for (; t < steps; ++t) {
        switch (t & 3) {
            case 0:  body(t, n0); break;
            case 1:  body(t, n1); break;
            case 2:  body(t, n2); break;
            default: body(t, n3); break;
        }
    }

    const float h = (float)half;
    f32x4 o;
    o[0] = acc[0] / h; o[1] = acc[1] / h; o[2] = acc[2] / h; o[3] = acc[3] / h;
    __builtin_nontemporal_store(o, reinterpret_cast<f32x4*>(out + (size_t)b * N + base));
}

extern "C" void kernel_launch(void* const* d_in, const int* in_sizes, int n_in,
                              void* d_out, int out_size, void* d_ws, size_t ws_size,
                              hipStream_t stream) {
    const float* cue    = (const float*)d_in[0];
    const float* W      = (const float*)d_in[1];
    const float* noise  = (const float*)d_in[2];
    const int*   steps  = (const int*)d_in[3];
    const int*   cuedur = (const int*)d_in[4];
    float*       out    = (float*)d_out;

    const int batch = in_sizes[0] / N;          // 128
    const size_t need = (size_t)N * N * 2;      // bf16 W

    if (ws_size >= need) {
        unsigned short* Wb = (unsigned short*)d_ws;
        conv_bf16<<<(N * N) / (256 * 8), 256, 0, stream>>>(W, Wb);
        attractor_sim<1><<<batch, BLK, 0, stream>>>(cue, W, Wb, noise, steps, cuedur, out, batch);
    } else {
        attractor_sim<0><<<batch, BLK, 0, stream>>>(cue, W, nullptr, noise, steps, cuedur, out, batch);
    }
}

// Round 4
// 480.843 us; speedup vs baseline: 1.8745x; 1.0350x over previous
//
#include <hip/hip_runtime.h>

// AttractorNetwork LIF, one workgroup per batch row.
// rec = last_spk @ ((W - inh/N)*(1-eye)) as a gather-sum over spike indices:
//   rec[n] = sum_{j in S} W[j][n] - k*c - (self ? (W[n][n]-c) : 0), c = inh/N
// W pre-converted to bf16 in d_ws (+ one extra all-zero pad row at index N).
//
// KEY fix this round: __syncthreads() forces `s_waitcnt vmcnt(0)` before
// s_barrier (hipcc semantics), draining the noise prefetch queue every step
// -> each of 200 steps paid a full HBM latency. Replaced with
// lgkmcnt(0)-only + raw s_barrier so noise loads stay in flight across steps.
// Gather: 16-wide with zero-row padding (no remainder latencies).

typedef float          f32x4 __attribute__((ext_vector_type(4)));
typedef unsigned int   u32x4 __attribute__((ext_vector_type(4)));
typedef unsigned int   u32x2 __attribute__((ext_vector_type(2)));
typedef unsigned short u16x8 __attribute__((ext_vector_type(8)));

constexpr int N    = 2048;   // neurons
constexpr int PT   = 4;      // neurons per thread
constexpr int BLK  = N / PT; // 512 threads = 8 waves
constexpr int ZROW = N;      // all-zero pad row index in Wb

__device__ __forceinline__ f32x4 ntload4(const float* p) {
    return __builtin_nontemporal_load(reinterpret_cast<const f32x4*>(p));
}
__device__ __forceinline__ float bf2f(unsigned b) {
    return __builtin_bit_cast(float, b << 16);
}
__device__ __forceinline__ void addrow_bf(f32x4& r, u32x2 v) {
    r[0] += __builtin_bit_cast(float, v[0] << 16);
    r[1] += __builtin_bit_cast(float, v[0] & 0xffff0000u);
    r[2] += __builtin_bit_cast(float, v[1] << 16);
    r[3] += __builtin_bit_cast(float, v[1] & 0xffff0000u);
}
// LDS-visibility-only barrier: do NOT drain vmcnt (keeps global prefetches
// in flight across steps). asm "memory" clobber pins memory-op order.
__device__ __forceinline__ void block_barrier() {
    asm volatile("s_waitcnt lgkmcnt(0)" ::: "memory");
    __builtin_amdgcn_s_barrier();
    __builtin_amdgcn_sched_barrier(0);
}

// ---- W f32 -> bf16 (RNE) pre-pass; writes N+1 rows (last row = zeros) ----
__global__ __launch_bounds__(256)
void conv_bf16(const float* __restrict__ W, unsigned short* __restrict__ Wb) {
    const size_t i = ((size_t)blockIdx.x * 256 + threadIdx.x) * 8;
    u16x8 o;
    if (i < (size_t)N * N) {
        const f32x4 a = *reinterpret_cast<const f32x4*>(W + i);
        const f32x4 b = *reinterpret_cast<const f32x4*>(W + i + 4);
        #pragma unroll
        for (int u = 0; u < 4; ++u) {
            const unsigned x = __builtin_bit_cast(unsigned, a[u]);
            o[u] = (unsigned short)((x + 0x7fffu + ((x >> 16) & 1u)) >> 16);
        }
        #pragma unroll
        for (int u = 0; u < 4; ++u) {
            const unsigned x = __builtin_bit_cast(unsigned, b[u]);
            o[4 + u] = (unsigned short)((x + 0x7fffu + ((x >> 16) & 1u)) >> 16);
        }
    } else {
        #pragma unroll
        for (int u = 0; u < 8; ++u) o[u] = 0;   // pad row
    }
    *reinterpret_cast<u16x8*>(Wb + i) = o;
}

// WM=1: bf16 gather from Wb (padded); WM=0: f32 gather from W (ws fallback)
template <int WM>
__global__ __launch_bounds__(BLK)
void attractor_sim(const float* __restrict__ cue,
                   const float* __restrict__ W,
                   const unsigned short* __restrict__ Wb,
                   const float* __restrict__ noise,
                   const int*   __restrict__ steps_p,
                   const int*   __restrict__ cuedur_p,
                   float*       __restrict__ out,
                   int batch)
{
    const int b    = blockIdx.x;
    const int tid  = threadIdx.x;
    const int base = tid * PT;
    const int lane = tid & 63;

    __shared__ __align__(16) unsigned short lst[3][N];
    __shared__ int cnt[3];
    if (tid < 3) cnt[tid] = 0;

    const int   steps  = *steps_p;      // 200
    const int   cuedur = *cuedur_p;     // 10
    const int   half   = steps / 2;
    const float decay  = 0.95122942450071400910f; // exp(-DT/TAU_MEM) as f32
    const float C_INH  = 0.1f / 2048.0f;

    const f32x4 ce = *reinterpret_cast<const f32x4*>(cue + (size_t)b * N + base);

    // diagonal (self-mask correction) from the SAME array the gather reads
    float wdiag[PT];
    #pragma unroll
    for (int u = 0; u < PT; ++u) {
        const size_t d = (size_t)(base + u) * N + (base + u);
        wdiag[u] = (WM == 1) ? bf2f((unsigned)Wb[d]) : W[d];
    }

    f32x4 mem = {0.f, 0.f, 0.f, 0.f};
    f32x4 acc = {0.f, 0.f, 0.f, 0.f};
    unsigned lastspk = 0;

    const size_t ss  = (size_t)batch * N;
    const float* nzp = noise + (size_t)b * N + base;

    // depth-4 noise pipeline (survives barriers now)
    f32x4 n0 = ntload4(nzp + (size_t)((0 < steps) ? 0 : steps - 1) * ss);
    f32x4 n1 = ntload4(nzp + (size_t)((1 < steps) ? 1 : steps - 1) * ss);
    f32x4 n2 = ntload4(nzp + (size_t)((2 < steps) ? 2 : steps - 1) * ss);
    f32x4 n3 = ntload4(nzp + (size_t)((3 < steps) ? 3 : steps - 1) * ss);

    int ra = 0, wb = 1, rc = 2;   // read / write / idle spike-list buffers

    block_barrier();

    auto body = [&](int t, f32x4& nReg) {
        const int k = cnt[ra];               // first: start LDS read early
        const f32x4 cur = nReg;
        const int tp = (t + 4 < steps) ? (t + 4) : (steps - 1);
        nReg = ntload4(nzp + (size_t)tp * ss);   // refill 4 steps ahead

        if (tid == 0) cnt[rc] = 0;           // idle buf; visible after barrier
        const unsigned short* lp = lst[ra];

        f32x4 r = {0.f, 0.f, 0.f, 0.f};
        if (WM == 1) {
            const int kp = (k + 15) & ~15;
            for (int i = 0; i < kp; i += 16) {
                const u32x4 iv0 = *reinterpret_cast<const u32x4*>(lp + i);
                const u32x4 iv1 = *reinterpret_cast<const u32x4*>(lp + i + 8);
                int j[16];
                #pragma unroll
                for (int u = 0; u < 4; ++u) {
                    j[2*u]     = (int)(iv0[u] & 0xffffu);
                    j[2*u + 1] = (int)(iv0[u] >> 16);
                    j[8 + 2*u]     = (int)(iv1[u] & 0xffffu);
                    j[8 + 2*u + 1] = (int)(iv1[u] >> 16);
                }
                #pragma unroll
                for (int u = 0; u < 16; ++u)
                    if (i + u >= k) j[u] = ZROW;      // pad -> zero row
                u32x2 v[16];
                #pragma unroll
                for (int u = 0; u < 16; ++u)
                    v[u] = *reinterpret_cast<const u32x2*>(Wb + (size_t)j[u] * N + base);
                #pragma unroll
                for (int u = 0; u < 16; ++u) addrow_bf(r, v[u]);
            }
        } else {
            int i = 0;
            for (; i + 8 <= k; i += 8) {
                const u32x4 iv = *reinterpret_cast<const u32x4*>(lp + i);
                const int j0 = (int)(iv[0] & 0xffffu), j1 = (int)(iv[0] >> 16);
                const int j2 = (int)(iv[1] & 0xffffu), j3 = (int)(iv[1] >> 16);
                const int j4 = (int)(iv[2] & 0xffffu), j5 = (int)(iv[2] >> 16);
                const int j6 = (int)(iv[3] & 0xffffu), j7 = (int)(iv[3] >> 16);
                const f32x4 w0 = *reinterpret_cast<const f32x4*>(W + (size_t)j0 * N + base);
                const f32x4 w1 = *reinterpret_cast<const f32x4*>(W + (size_t)j1 * N + base);
                const f32x4 w2 = *reinterpret_cast<const f32x4*>(W + (size_t)j2 * N + base);
                const f32x4 w3 = *reinterpret_cast<const f32x4*>(W + (size_t)j3 * N + base);
                const f32x4 w4 = *reinterpret_cast<const f32x4*>(W + (size_t)j4 * N + base);
                const f32x4 w5 = *reinterpret_cast<const f32x4*>(W + (size_t)j5 * N + base);
                const f32x4 w6 = *reinterpret_cast<const f32x4*>(W + (size_t)j6 * N + base);
                const f32x4 w7 = *reinterpret_cast<const f32x4*>(W + (size_t)j7 * N + base);
                r += w0; r += w1; r += w2; r += w3;
                r += w4; r += w5; r += w6; r += w7;
            }
            for (; i < k; ++i)
                r += *reinterpret_cast<const f32x4*>(W + (size_t)lp[i] * N + base);
        }

        const float corr   = (float)k * C_INH;
        const bool  in_cue = (t < cuedur);

        unsigned newspk = 0;
        bool sp[PT];
        #pragma unroll
        for (int u = 0; u < PT; ++u) {
            float rec = r[u] - corr;
            if (lastspk & (1u << u)) rec -= (wdiag[u] - C_INH);
            const float ext = in_cue ? ce[u] : 0.0f;
            const float m   = mem[u] * decay + (rec + ext) + cur[u];
            sp[u] = (m >= 1.0f);
            if (sp[u]) {
                mem[u] = 0.0f;
                newspk |= (1u << u);
                if (t >= half) acc[u] += 1.0f;
            } else {
                mem[u] = m;
            }
        }
        lastspk = newspk;

        // per-wave ballot compaction: 1 atomic per wave per sub-neuron slot
        #pragma unroll
        for (int u = 0; u < PT; ++u) {
            const unsigned long long msk = __ballot(sp[u]);
            if (msk) {
                int wpos;
                if (lane == 0) wpos = atomicAdd(&cnt[wb], __popcll(msk));
                wpos = __shfl(wpos, 0);
                if (sp[u]) {
                    const int off = __popcll(msk & ((1ull << lane) - 1ull));
                    lst[wb][wpos + off] = (unsigned short)(base + u);
                }
            }
        }

        block_barrier();   // lgkmcnt-only: vmem prefetches stay in flight
        const int t0 = ra; ra = wb; wb = rc; rc = t0;
    };

    int t = 0;
    for (; t + 4 <= steps; t += 4) {
        body(t,     n0);
        body(t + 1, n1);
        body(t + 2, n2);
        body(t + 3, n3);
    }
    for (; t < steps; ++t) {
        switch (t & 3) {
            case 0:  body(t, n0); break;
            case 1:  body(t, n1); break;
            case 2:  body(t, n2); break;
            default: body(t, n3); break;
        }
    }

    const float h = (float)half;
    f32x4 o;
    o[0] = acc[0] / h; o[1] = acc[1] / h; o[2] = acc[2] / h; o[3] = acc[3] / h;
    __builtin_nontemporal_store(o, reinterpret_cast<f32x4*>(out + (size_t)b * N + base));
}

extern "C" void kernel_launch(void* const* d_in, const int* in_sizes, int n_in,
                              void* d_out, int out_size, void* d_ws, size_t ws_size,
                              hipStream_t stream) {
    const float* cue    = (const float*)d_in[0];
    const float* W      = (const float*)d_in[1];
    const float* noise  = (const float*)d_in[2];
    const int*   steps  = (const int*)d_in[3];
    const int*   cuedur = (const int*)d_in[4];
    float*       out    = (float*)d_out;

    const int batch = in_sizes[0] / N;              // 128
    const size_t need = (size_t)(N + 1) * N * 2;    // bf16 W + zero pad row

    if (ws_size >= need) {
        unsigned short* Wb = (unsigned short*)d_ws;
        conv_bf16<<<(N + 1) * (N / (256 * 8)), 256, 0, stream>>>(W, Wb);
        attractor_sim<1><<<batch, BLK, 0, stream>>>(cue, W, Wb, noise, steps, cuedur, out, batch);
    } else {
        attractor_sim<0><<<batch, BLK, 0, stream>>>(cue, W, nullptr, noise, steps, cuedur, out, batch);
    }
}